// Round 10
// baseline (592.761 us; speedup 1.0000x reference)
//
#include <hip/hip_runtime.h>
#include <hip/hip_bf16.h>
#include <stdint.h>

#define NTOK 8192   // B*S
#define MDIM 1024
#define HDIM 4096
#define NEXP 8
#define CAP  2048   // int(1.0 * 2 * 8192 // 8)

typedef __attribute__((ext_vector_type(8))) short bf16x8;
typedef __attribute__((ext_vector_type(4))) float f32x4;

__device__ __forceinline__ ushort f2bf(float f) {
  uint32_t u = __builtin_bit_cast(uint32_t, f);
  u += 0x7FFFu + ((u >> 16) & 1u);          // round-to-nearest-even
  return (ushort)(u >> 16);
}
__device__ __forceinline__ float bf2f(ushort h) {
  uint32_t u = ((uint32_t)h) << 16;
  return __builtin_bit_cast(float, u);
}

// async global->LDS, 16B per lane; LDS dest = wave-uniform base + lane*16
#define GLOAD_LDS16(g, l)                                                    \
  __builtin_amdgcn_global_load_lds(                                          \
      (const __attribute__((address_space(1))) void*)(g),                    \
      (__attribute__((address_space(3))) void*)(l), 16, 0, 0)

// ---------------- gate: logits = x@wg (f64 accum), softmax-top2, normalize ----
__global__ __launch_bounds__(256) void gate_kernel(const float* __restrict__ x,
                                                   const float* __restrict__ wg,
                                                   int* __restrict__ topi,
                                                   float* __restrict__ gatev) {
  const int lane = threadIdx.x & 63;
  const int n = blockIdx.x * 4 + (threadIdx.x >> 6);   // one wave per token
  const float* xr = x + (size_t)n * MDIM;
  double acc[NEXP];
#pragma unroll
  for (int e = 0; e < NEXP; ++e) acc[e] = 0.0;
#pragma unroll
  for (int c = 0; c < 4; ++c) {
    float4 xv = *(const float4*)(xr + c * 256 + lane * 4);
    float xs[4] = {xv.x, xv.y, xv.z, xv.w};
#pragma unroll
    for (int j = 0; j < 4; ++j) {
      int m = c * 256 + lane * 4 + j;
      float4 w0 = *(const float4*)(wg + m * 8);
      float4 w1 = *(const float4*)(wg + m * 8 + 4);
      double xd = (double)xs[j];
      acc[0] += xd * (double)w0.x; acc[1] += xd * (double)w0.y;
      acc[2] += xd * (double)w0.z; acc[3] += xd * (double)w0.w;
      acc[4] += xd * (double)w1.x; acc[5] += xd * (double)w1.y;
      acc[6] += xd * (double)w1.z; acc[7] += xd * (double)w1.w;
    }
  }
#pragma unroll
  for (int off = 32; off >= 1; off >>= 1) {
#pragma unroll
    for (int e = 0; e < NEXP; ++e) acc[e] += __shfl_xor(acc[e], off, 64);
  }
  if (lane == 0) {
    int i0 = 0;
#pragma unroll
    for (int e = 1; e < NEXP; ++e) if (acc[e] > acc[i0]) i0 = e;
    int i1 = (i0 == 0) ? 1 : 0;
#pragma unroll
    for (int e = 0; e < NEXP; ++e) if (e != i0 && acc[e] > acc[i1]) i1 = e;
    // normalized top-2 of softmax == softmax over the two logits
    double e1 = exp(acc[i1] - acc[i0]);
    double s = 1.0 + e1;
    topi[n * 2 + 0] = i0; topi[n * 2 + 1] = i1;
    gatev[n * 2 + 0] = (float)(1.0 / s);
    gatev[n * 2 + 1] = (float)(e1 / s);
  }
}

// ---------------- slot-major cumulative positions (order: j = k*NTOK + n) ----
__global__ __launch_bounds__(256) void scan_kernel(const int* __restrict__ topi,
                                                   int* __restrict__ pos) {
  __shared__ int cnt[256][NEXP];
  const int t = threadIdx.x;
#pragma unroll
  for (int e = 0; e < NEXP; ++e) cnt[t][e] = 0;
  for (int i = 0; i < 64; ++i) {
    int j = t * 64 + i;
    int e = topi[(j & (NTOK - 1)) * 2 + (j >> 13)];
    cnt[t][e]++;
  }
  __syncthreads();
  if (t < NEXP) {          // exclusive scan over the 256 thread-chunks
    int run = 0;
    for (int i = 0; i < 256; ++i) { int v = cnt[i][t]; cnt[i][t] = run; run += v; }
  }
  __syncthreads();
  for (int i = 0; i < 64; ++i) {
    int j = t * 64 + i;
    int idx = (j & (NTOK - 1)) * 2 + (j >> 13);
    int e = topi[idx];
    pos[idx] = cnt[t][e]++;
  }
}

// ---------------- scatter x rows (bf16) into [E,CAP,M] -----------------------
// No zero-fill of disp needed: garbage rows are never read downstream.
__global__ __launch_bounds__(256) void scatter_kernel(const float* __restrict__ x,
                                                      const int* __restrict__ topi,
                                                      const int* __restrict__ pos,
                                                      ushort* __restrict__ disp) {
  const int lane = threadIdx.x & 63;
  const int n = blockIdx.x * 4 + (threadIdx.x >> 6);
  const float* src = x + (size_t)n * MDIM;
  ushort b[16];
#pragma unroll
  for (int c = 0; c < 4; ++c) {
    float4 v = *(const float4*)(src + c * 256 + lane * 4);
    b[c * 4 + 0] = f2bf(v.x); b[c * 4 + 1] = f2bf(v.y);
    b[c * 4 + 2] = f2bf(v.z); b[c * 4 + 3] = f2bf(v.w);
  }
#pragma unroll
  for (int k = 0; k < 2; ++k) {
    int p = pos[n * 2 + k];
    if (p < CAP) {
      int e = topi[n * 2 + k];
      ushort* dst = disp + ((size_t)(e * CAP + p)) * MDIM;
#pragma unroll
      for (int c = 0; c < 4; ++c) {
        ushort4 o; o.x = b[c*4+0]; o.y = b[c*4+1]; o.z = b[c*4+2]; o.w = b[c*4+3];
        *(ushort4*)(dst + c * 256 + lane * 4) = o;
      }
    }
  }
}

// ---------------- transpose + f32->bf16: in[R][C] -> out[C][R], per expert ---
__global__ __launch_bounds__(256) void transpose_cvt(const float* __restrict__ in,
                                                     ushort* __restrict__ out,
                                                     int R, int C) {
  __shared__ float tile[64][65];
  const int e = blockIdx.z;
  in  += (size_t)e * R * C;
  out += (size_t)e * R * C;
  const int r0 = blockIdx.y * 64, c0 = blockIdx.x * 64;
  const int t = threadIdx.x;
  const int r = t >> 2, cq = t & 3;
#pragma unroll
  for (int i = 0; i < 4; ++i) {
    float4 v = *(const float4*)(in + (size_t)(r0 + r) * C + c0 + cq * 16 + i * 4);
    tile[r][cq * 16 + i * 4 + 0] = v.x; tile[r][cq * 16 + i * 4 + 1] = v.y;
    tile[r][cq * 16 + i * 4 + 2] = v.z; tile[r][cq * 16 + i * 4 + 3] = v.w;
  }
  __syncthreads();
  const int oc = t >> 2, orr0 = (t & 3) * 16;
  ushort o16[16];
#pragma unroll
  for (int i = 0; i < 16; ++i) o16[i] = f2bf(tile[orr0 + i][oc]);
  ushort* dst = out + (size_t)(c0 + oc) * R + r0 + orr0;
  *(uint4*)dst = *(uint4*)&o16[0];
  *(uint4*)(dst + 8) = *(uint4*)&o16[8];
}

// ============================================================================
// 256x256x64 bf16 GEMM, 4-wave / 128x128-wave-tile (round 10):
// Structural change from rounds 3-9 (all 8-wave variants, MfmaUtil 40+-3%):
// LDS panel traffic per tile was 8 waves x (16KB A + 8KB B) = 192KB = 2304cy,
// ~= MFMA 2480cy -> no schedule could exceed ~50%. With 4 waves x 128x128
// tile: 4 x (16+16)KB = 128KB = 1536cy << MFMA 2480cy, and per-window reads
// (768cy/CU) fit UNDER the 64-MFMA window (1240cy/SIMD). Frags are
// cross-window prefetched (kk1 reads before MFMA kk0; next-tile kk0 reads
// after mid-tile barrier, before MFMA kk1) so no MFMA waits on a same-window
// read. acc[8][8]=256 regs + 2x64 frag regs ~= 410 -> 1 wave/SIMD, which the
// 128KB LDS forces anyway (1 block/CU); launch_bounds(256,1) unlocks the
// 512-reg budget. 64 independent accumulators keep the matrix pipe full from
// a single wave. Staging/swizzle identical (16 gloads/thread/tile; VM0
// mid-tile sits ~1300cy after issue > 900cy HBM latency; 2 barriers/tile,
// ledger re-verified for 4 waves).
// ============================================================================
template <bool RELU>
__global__ __launch_bounds__(256, 1) void gemm4w(const ushort* __restrict__ Ag,
                                                 const ushort* __restrict__ Btg,
                                                 const float* __restrict__ biasg,
                                                 ushort* __restrict__ Cout,
                                                 int Mrows, int Ncols, int Kdim) {
  __shared__ ushort sh[65536];   // 128 KiB
  // bijective XCD swizzle (grids are %8==0)
  const int gx = gridDim.x, gy = gridDim.y;
  const int nwg = gx * gy * gridDim.z;
  const int lin = blockIdx.x + gx * (blockIdx.y + gy * blockIdx.z);
  const int cpx = nwg >> 3;
  const int swz = (lin & 7) * cpx + (lin >> 3);
  const int gxy = gx * gy;
  const int ez = swz / gxy;
  const int rem = swz - ez * gxy;
  const int by = rem / gx;
  const int bx = rem - by * gx;

  const ushort* A  = Ag  + (size_t)ez * Mrows * Kdim;
  const ushort* Bt = Btg + (size_t)ez * Ncols * Kdim;
  const float* bias = biasg + (size_t)ez * Ncols;
  ushort* Cptr = Cout + (size_t)ez * Mrows * Ncols;
  const int m0 = by * 256, n0 = bx * 256;
  const int t = threadIdx.x, lane = t & 63, w = t >> 6;   // w in [0,4)
  const int l15 = lane & 15, l4 = lane >> 4;
  const int wr = w >> 1, wc = w & 1;      // 2x2 wave grid, wave tile 128x128

  // ---- staging addressing: wave w + seg s covers rows s*32 + w*8 + srow ----
  const int srow = lane >> 3;             // 0..7 row within 8-row slab
  const int cs = (lane & 7) ^ srow;       // pre-swizzled source chunk
  const ushort* Abase = A  + (size_t)(m0 + w * 8 + srow) * Kdim + cs * 8;
  const ushort* Bbase = Bt + (size_t)(n0 + w * 8 + srow) * Kdim + cs * 8;
  const int ldsw = w * 512;               // wave-uniform LDS offset (ushorts)

  // stage one half (128 rows x 64 K) of A or B: 4 gloads/thread (4 segs)
#define STAGE(isA, d, half, ktile)                                          \
  do {                                                                      \
    const ushort* gb = ((isA) ? Abase : Bbase) +                            \
                       (size_t)((half) * 128) * Kdim + (ktile) * 64;        \
    ushort* lb = sh + ((isA) ? 0 : 32768) + ((d) * 2 + (half)) * 8192 + ldsw;\
    _Pragma("unroll") for (int s_ = 0; s_ < 4; ++s_)                        \
      GLOAD_LDS16(gb + (size_t)(s_ * 32) * Kdim, lb + s_ * 2048);           \
  } while (0)

  // ---- fragment-read addressing (conflict-free l15/l4 pattern) ----
  const int chk0 = ((0 + l4) ^ (l15 & 7)) * 8;   // kk=0 chunk (ushorts)
  const int chk1 = ((4 + l4) ^ (l15 & 7)) * 8;   // kk=1 chunk
  const int aoff = l15 * 64;
  const int boff = l15 * 64;

  bf16x8 a0[8], b0[8];   // frag set for kk even
  bf16x8 a1[8], b1[8];   // frag set for kk odd

#define READ_K(d, kk, AF, BF)                                                \
  { const int ck = (kk) ? chk1 : chk0;                                       \
    const ushort* Ar = sh + ((d) * 2 + wr) * 8192 + aoff + ck;               \
    const ushort* Br = sh + 32768 + ((d) * 2 + wc) * 8192 + boff + ck;       \
    _Pragma("unroll") for (int m_ = 0; m_ < 8; ++m_)                         \
      AF[m_] = *(const bf16x8*)(Ar + m_ * 1024);                             \
    _Pragma("unroll") for (int n_ = 0; n_ < 8; ++n_)                         \
      BF[n_] = *(const bf16x8*)(Br + n_ * 1024);                             \
  }

#define MFMA64(AF, BF)                                                       \
  _Pragma("unroll") for (int m_ = 0; m_ < 8; ++m_)                           \
    _Pragma("unroll") for (int n_ = 0; n_ < 8; ++n_)                         \
      acc[m_][n_] = __builtin_amdgcn_mfma_f32_16x16x32_bf16(                 \
          AF[m_], BF[n_], acc[m_][n_], 0, 0, 0);

#define SB  __builtin_amdgcn_sched_barrier(0)
#define BAR __builtin_amdgcn_s_barrier()
#define VM0 asm volatile("s_waitcnt vmcnt(0)" ::: "memory")

  f32x4 acc[8][8];
#pragma unroll
  for (int i = 0; i < 8; ++i)
#pragma unroll
    for (int j = 0; j < 8; ++j) acc[i][j] = (f32x4){0.f, 0.f, 0.f, 0.f};

  const int NT = Kdim >> 6;
  // prologue: stage tile 0 into buf 0; pre-read kk0 frags
  STAGE(1, 0, 0, 0); STAGE(1, 0, 1, 0);
  STAGE(0, 0, 0, 0); STAGE(0, 0, 1, 0);
  VM0; SB; BAR;
  READ_K(0, 0, a0, b0)

  for (int kt = 0; kt < NT; ++kt) {
    const int d = kt & 1;
    const bool more = (kt + 1) < NT;
    // ---- W0: stage t+1; read kk1; MFMA kk0 (frags from previous window) ----
    if (more) {
      STAGE(1, d ^ 1, 0, kt + 1); STAGE(1, d ^ 1, 1, kt + 1);
      STAGE(0, d ^ 1, 0, kt + 1); STAGE(0, d ^ 1, 1, kt + 1);
    }
    READ_K(d, 1, a1, b1)
    MFMA64(a0, b0)
    SB; VM0; BAR;            // t+1 staged (issued ~1300cy ago) + visible
    // ---- W1: read next tile's kk0 from other buf; MFMA kk1 ----
    if (more) { READ_K(d ^ 1, 0, a0, b0) }
    MFMA64(a1, b1)
    SB; BAR;                 // all reads of buf d consumed; t+2 may overwrite
  }

  // epilogue: D[row=(l>>4)*4+r][col=l&15] per 16x16 frag
#pragma unroll
  for (int m = 0; m < 8; ++m) {
    const int rowb = m0 + wr * 128 + m * 16 + l4 * 4;
#pragma unroll
    for (int n = 0; n < 8; ++n) {
      const int col = n0 + wc * 128 + n * 16 + l15;
      const float bv = bias[col];
      f32x4 v = acc[m][n];
#pragma unroll
      for (int r = 0; r < 4; ++r) {
        float f = v[r] + bv;
        if (RELU) f = fmaxf(f, 0.f);
        Cptr[(size_t)(rowb + r) * Ncols + col] = f2bf(f);
      }
    }
  }
#undef STAGE
#undef READ_K
#undef MFMA64
#undef SB
#undef BAR
#undef VM0
}

// ---------------- combine: out[n] = sum_k gate * y[e_k, p_k] -----------------
__global__ __launch_bounds__(256) void combine_kernel(const ushort* __restrict__ y,
                                                      const int* __restrict__ topi,
                                                      const int* __restrict__ pos,
                                                      const float* __restrict__ gatev,
                                                      float* __restrict__ out) {
  const int lane = threadIdx.x & 63;
  const int n = blockIdx.x * 4 + (threadIdx.x >> 6);
  int i0 = topi[n * 2], i1 = topi[n * 2 + 1];
  int p0 = pos[n * 2], p1 = pos[n * 2 + 1];
  float g0 = (p0 < CAP) ? gatev[n * 2] : 0.f;
  float g1 = (p1 < CAP) ? gatev[n * 2 + 1] : 0.f;
  const ushort* y0 = y + (size_t)(i0 * CAP + (p0 < CAP ? p0 : 0)) * MDIM;
  const ushort* y1 = y + (size_t)(i1 * CAP + (p1 < CAP ? p1 : 0)) * MDIM;
  float* o = out + (size_t)n * MDIM;
#pragma unroll
  for (int c = 0; c < 4; ++c) {
    int idx = c * 256 + lane * 4;
    ushort4 a = *(const ushort4*)(y0 + idx);
    ushort4 b = *(const ushort4*)(y1 + idx);
    float4 ov;
    ov.x = g0 * bf2f(a.x) + g1 * bf2f(b.x);
    ov.y = g0 * bf2f(a.y) + g1 * bf2f(b.y);
    ov.z = g0 * bf2f(a.z) + g1 * bf2f(b.z);
    ov.w = g0 * bf2f(a.w) + g1 * bf2f(b.w);
    *(float4*)(o + idx) = ov;
  }
}

extern "C" void kernel_launch(void* const* d_in, const int* in_sizes, int n_in,
                              void* d_out, int out_size, void* d_ws, size_t ws_size,
                              hipStream_t stream) {
  const float* x  = (const float*)d_in[0];
  const float* wg = (const float*)d_in[1];
  const float* w1 = (const float*)d_in[2];
  const float* b1 = (const float*)d_in[3];
  const float* w2 = (const float*)d_in[4];
  const float* b2 = (const float*)d_in[5];
  float* out = (float*)d_out;
  char* ws = (char*)d_ws;

  // workspace layout (224.3 MB total)
  int*    topi  = (int*)(ws);
  int*    pos   = (int*)(ws + 65536);
  float*  gatev = (float*)(ws + 131072);
  ushort* dispb = (ushort*)(ws + 262144);                          // 32MB, reused as y
  ushort* wT    = (ushort*)(ws + 262144 + 33554432);               // 64MB (w1t then w2t)
  ushort* hbuf  = (ushort*)(ws + 262144 + 33554432 + 67108864);    // 128MB

  gate_kernel<<<NTOK / 4, 256, 0, stream>>>(x, wg, topi, gatev);
  scan_kernel<<<1, 256, 0, stream>>>(topi, pos);
  // no zero_kernel: disp rows p >= count[e] are never read downstream
  scatter_kernel<<<NTOK / 4, 256, 0, stream>>>(x, topi, pos, dispb);

  // FFN layer 1: h = relu(disp @ w1 + b1)   [E,2048,1024]x[E,1024,4096]
  transpose_cvt<<<dim3(HDIM / 64, MDIM / 64, NEXP), 256, 0, stream>>>(w1, wT, MDIM, HDIM);
  gemm4w<true><<<dim3(HDIM / 256, CAP / 256, NEXP), 256, 0, stream>>>(
      dispb, wT, b1, hbuf, CAP, HDIM, MDIM);

  // FFN layer 2: y = h @ w2 + b2            [E,2048,4096]x[E,4096,1024]
  transpose_cvt<<<dim3(MDIM / 64, HDIM / 64, NEXP), 256, 0, stream>>>(w2, wT, HDIM, MDIM);
  ushort* ybuf = dispb;  // dispb is dead after GEMM1
  gemm4w<false><<<dim3(MDIM / 256, CAP / 256, NEXP), 256, 0, stream>>>(
      hbuf, wT, b2, ybuf, CAP, MDIM, HDIM);

  combine_kernel<<<NTOK / 4, 256, 0, stream>>>(ybuf, topi, pos, gatev, out);
}

// Round 11
// 484.748 us; speedup vs baseline: 1.2228x; 1.2228x over previous
//
#include <hip/hip_runtime.h>
#include <hip/hip_bf16.h>
#include <stdint.h>

#define NTOK 8192   // B*S
#define MDIM 1024
#define HDIM 4096
#define NEXP 8
#define CAP  2048   // int(1.0 * 2 * 8192 // 8)

typedef __attribute__((ext_vector_type(8))) short bf16x8;
typedef __attribute__((ext_vector_type(4))) float f32x4;

__device__ __forceinline__ ushort f2bf(float f) {
  uint32_t u = __builtin_bit_cast(uint32_t, f);
  u += 0x7FFFu + ((u >> 16) & 1u);          // round-to-nearest-even
  return (ushort)(u >> 16);
}
__device__ __forceinline__ float bf2f(ushort h) {
  uint32_t u = ((uint32_t)h) << 16;
  return __builtin_bit_cast(float, u);
}

// async global->LDS, 16B per lane; LDS dest = wave-uniform base + lane*16
#define GLOAD_LDS16(g, l)                                                    \
  __builtin_amdgcn_global_load_lds(                                          \
      (const __attribute__((address_space(1))) void*)(g),                    \
      (__attribute__((address_space(3))) void*)(l), 16, 0, 0)

// ---------------- gate: logits = x@wg (f64 accum), softmax-top2, normalize ----
__global__ __launch_bounds__(256) void gate_kernel(const float* __restrict__ x,
                                                   const float* __restrict__ wg,
                                                   int* __restrict__ topi,
                                                   float* __restrict__ gatev) {
  const int lane = threadIdx.x & 63;
  const int n = blockIdx.x * 4 + (threadIdx.x >> 6);   // one wave per token
  const float* xr = x + (size_t)n * MDIM;
  double acc[NEXP];
#pragma unroll
  for (int e = 0; e < NEXP; ++e) acc[e] = 0.0;
#pragma unroll
  for (int c = 0; c < 4; ++c) {
    float4 xv = *(const float4*)(xr + c * 256 + lane * 4);
    float xs[4] = {xv.x, xv.y, xv.z, xv.w};
#pragma unroll
    for (int j = 0; j < 4; ++j) {
      int m = c * 256 + lane * 4 + j;
      float4 w0 = *(const float4*)(wg + m * 8);
      float4 w1 = *(const float4*)(wg + m * 8 + 4);
      double xd = (double)xs[j];
      acc[0] += xd * (double)w0.x; acc[1] += xd * (double)w0.y;
      acc[2] += xd * (double)w0.z; acc[3] += xd * (double)w0.w;
      acc[4] += xd * (double)w1.x; acc[5] += xd * (double)w1.y;
      acc[6] += xd * (double)w1.z; acc[7] += xd * (double)w1.w;
    }
  }
#pragma unroll
  for (int off = 32; off >= 1; off >>= 1) {
#pragma unroll
    for (int e = 0; e < NEXP; ++e) acc[e] += __shfl_xor(acc[e], off, 64);
  }
  if (lane == 0) {
    int i0 = 0;
#pragma unroll
    for (int e = 1; e < NEXP; ++e) if (acc[e] > acc[i0]) i0 = e;
    int i1 = (i0 == 0) ? 1 : 0;
#pragma unroll
    for (int e = 0; e < NEXP; ++e) if (e != i0 && acc[e] > acc[i1]) i1 = e;
    // normalized top-2 of softmax == softmax over the two logits
    double e1 = exp(acc[i1] - acc[i0]);
    double s = 1.0 + e1;
    topi[n * 2 + 0] = i0; topi[n * 2 + 1] = i1;
    gatev[n * 2 + 0] = (float)(1.0 / s);
    gatev[n * 2 + 1] = (float)(e1 / s);
  }
}

// ---------------- slot-major cumulative positions (order: j = k*NTOK + n) ----
__global__ __launch_bounds__(256) void scan_kernel(const int* __restrict__ topi,
                                                   int* __restrict__ pos) {
  __shared__ int cnt[256][NEXP];
  const int t = threadIdx.x;
#pragma unroll
  for (int e = 0; e < NEXP; ++e) cnt[t][e] = 0;
  for (int i = 0; i < 64; ++i) {
    int j = t * 64 + i;
    int e = topi[(j & (NTOK - 1)) * 2 + (j >> 13)];
    cnt[t][e]++;
  }
  __syncthreads();
  if (t < NEXP) {          // exclusive scan over the 256 thread-chunks
    int run = 0;
    for (int i = 0; i < 256; ++i) { int v = cnt[i][t]; cnt[i][t] = run; run += v; }
  }
  __syncthreads();
  for (int i = 0; i < 64; ++i) {
    int j = t * 64 + i;
    int idx = (j & (NTOK - 1)) * 2 + (j >> 13);
    int e = topi[idx];
    pos[idx] = cnt[t][e]++;
  }
}

// ---------------- scatter x rows (bf16) into [E,CAP,M] -----------------------
// No zero-fill of disp needed: garbage rows are never read downstream.
__global__ __launch_bounds__(256) void scatter_kernel(const float* __restrict__ x,
                                                      const int* __restrict__ topi,
                                                      const int* __restrict__ pos,
                                                      ushort* __restrict__ disp) {
  const int lane = threadIdx.x & 63;
  const int n = blockIdx.x * 4 + (threadIdx.x >> 6);
  const float* src = x + (size_t)n * MDIM;
  ushort b[16];
#pragma unroll
  for (int c = 0; c < 4; ++c) {
    float4 v = *(const float4*)(src + c * 256 + lane * 4);
    b[c * 4 + 0] = f2bf(v.x); b[c * 4 + 1] = f2bf(v.y);
    b[c * 4 + 2] = f2bf(v.z); b[c * 4 + 3] = f2bf(v.w);
  }
#pragma unroll
  for (int k = 0; k < 2; ++k) {
    int p = pos[n * 2 + k];
    if (p < CAP) {
      int e = topi[n * 2 + k];
      ushort* dst = disp + ((size_t)(e * CAP + p)) * MDIM;
#pragma unroll
      for (int c = 0; c < 4; ++c) {
        ushort4 o; o.x = b[c*4+0]; o.y = b[c*4+1]; o.z = b[c*4+2]; o.w = b[c*4+3];
        *(ushort4*)(dst + c * 256 + lane * 4) = o;
      }
    }
  }
}

// ---------------- transpose + f32->bf16: in[R][C] -> out[C][R], per expert ---
__global__ __launch_bounds__(256) void transpose_cvt(const float* __restrict__ in,
                                                     ushort* __restrict__ out,
                                                     int R, int C) {
  __shared__ float tile[64][65];
  const int e = blockIdx.z;
  in  += (size_t)e * R * C;
  out += (size_t)e * R * C;
  const int r0 = blockIdx.y * 64, c0 = blockIdx.x * 64;
  const int t = threadIdx.x;
  const int r = t >> 2, cq = t & 3;
#pragma unroll
  for (int i = 0; i < 4; ++i) {
    float4 v = *(const float4*)(in + (size_t)(r0 + r) * C + c0 + cq * 16 + i * 4);
    tile[r][cq * 16 + i * 4 + 0] = v.x; tile[r][cq * 16 + i * 4 + 1] = v.y;
    tile[r][cq * 16 + i * 4 + 2] = v.z; tile[r][cq * 16 + i * 4 + 3] = v.w;
  }
  __syncthreads();
  const int oc = t >> 2, orr0 = (t & 3) * 16;
  ushort o16[16];
#pragma unroll
  for (int i = 0; i < 16; ++i) o16[i] = f2bf(tile[orr0 + i][oc]);
  ushort* dst = out + (size_t)(c0 + oc) * R + r0 + orr0;
  *(uint4*)dst = *(uint4*)&o16[0];
  *(uint4*)(dst + 8) = *(uint4*)&o16[8];
}

// ============================================================================
// 256x256x64 bf16 GEMM, 4-wave / 128x128 wave-tile, AGPR accumulators
// (round 11 = round 10 + inline-asm MFMA with "+a" constraint):
// Round 10's structure was correct (validated; conflicts 0) but the builtin
// MFMA path let the allocator cap at 256 arch VGPRs -> acc shuttling/spill
// (VGPR=256, VALUBusy 32%, MfmaUtil 21.7%). Fix: acc[8][8] f32x4 = exactly
// 256 AGPRs pinned via inline asm (MFMA reads/writes AGPR C/D natively, no
// v_accvgpr traffic in the loop); frags 4x8 bf16x8 = 128 VGPR + addressing
// ~40 -> fits the 256-VGPR file at 1 wave/SIMD (which 128KB LDS forces
// anyway). Per-CU LDS panel traffic drops 192->128 KB/tile vs the 8-wave
// plateau (no cross-wave panel duplication); reads (~570cy/window) hide
// under the 64-MFMA windows (1240cy/SIMD) via cross-window prefetch
// (kk1 reads before MFMA kk0; next-tile kk0 after mid-tile barrier).
// No setprio (no co-wave). Staging/swizzle/ledger = round 10 verbatim.
// ============================================================================
template <bool RELU>
__global__ __launch_bounds__(256, 1) void gemm4w(const ushort* __restrict__ Ag,
                                                 const ushort* __restrict__ Btg,
                                                 const float* __restrict__ biasg,
                                                 ushort* __restrict__ Cout,
                                                 int Mrows, int Ncols, int Kdim) {
  __shared__ ushort sh[65536];   // 128 KiB
  // bijective XCD swizzle (grids are %8==0)
  const int gx = gridDim.x, gy = gridDim.y;
  const int nwg = gx * gy * gridDim.z;
  const int lin = blockIdx.x + gx * (blockIdx.y + gy * blockIdx.z);
  const int cpx = nwg >> 3;
  const int swz = (lin & 7) * cpx + (lin >> 3);
  const int gxy = gx * gy;
  const int ez = swz / gxy;
  const int rem = swz - ez * gxy;
  const int by = rem / gx;
  const int bx = rem - by * gx;

  const ushort* A  = Ag  + (size_t)ez * Mrows * Kdim;
  const ushort* Bt = Btg + (size_t)ez * Ncols * Kdim;
  const float* bias = biasg + (size_t)ez * Ncols;
  ushort* Cptr = Cout + (size_t)ez * Mrows * Ncols;
  const int m0 = by * 256, n0 = bx * 256;
  const int t = threadIdx.x, lane = t & 63, w = t >> 6;   // w in [0,4)
  const int l15 = lane & 15, l4 = lane >> 4;
  const int wr = w >> 1, wc = w & 1;      // 2x2 wave grid, wave tile 128x128

  // ---- staging addressing: wave w + seg s covers rows s*32 + w*8 + srow ----
  const int srow = lane >> 3;             // 0..7 row within 8-row slab
  const int cs = (lane & 7) ^ srow;       // pre-swizzled source chunk
  const ushort* Abase = A  + (size_t)(m0 + w * 8 + srow) * Kdim + cs * 8;
  const ushort* Bbase = Bt + (size_t)(n0 + w * 8 + srow) * Kdim + cs * 8;
  const int ldsw = w * 512;               // wave-uniform LDS offset (ushorts)

  // stage one half (128 rows x 64 K) of A or B: 4 gloads/thread (4 segs)
#define STAGE(isA, d, half, ktile)                                          \
  do {                                                                      \
    const ushort* gb = ((isA) ? Abase : Bbase) +                            \
                       (size_t)((half) * 128) * Kdim + (ktile) * 64;        \
    ushort* lb = sh + ((isA) ? 0 : 32768) + ((d) * 2 + (half)) * 8192 + ldsw;\
    _Pragma("unroll") for (int s_ = 0; s_ < 4; ++s_)                        \
      GLOAD_LDS16(gb + (size_t)(s_ * 32) * Kdim, lb + s_ * 2048);           \
  } while (0)

  // ---- fragment-read addressing (conflict-free l15/l4 pattern) ----
  const int chk0 = ((0 + l4) ^ (l15 & 7)) * 8;   // kk=0 chunk (ushorts)
  const int chk1 = ((4 + l4) ^ (l15 & 7)) * 8;   // kk=1 chunk
  const int aoff = l15 * 64;
  const int boff = l15 * 64;

  bf16x8 a0[8], b0[8];   // frag set for kk even
  bf16x8 a1[8], b1[8];   // frag set for kk odd

#define READ_K(d, kk, AF, BF)                                                \
  { const int ck = (kk) ? chk1 : chk0;                                       \
    const ushort* Ar = sh + ((d) * 2 + wr) * 8192 + aoff + ck;               \
    const ushort* Br = sh + 32768 + ((d) * 2 + wc) * 8192 + boff + ck;       \
    _Pragma("unroll") for (int m_ = 0; m_ < 8; ++m_)                         \
      AF[m_] = *(const bf16x8*)(Ar + m_ * 1024);                             \
    _Pragma("unroll") for (int n_ = 0; n_ < 8; ++n_)                         \
      BF[n_] = *(const bf16x8*)(Br + n_ * 1024);                             \
  }

  // AGPR-pinned MFMA: D/C stay in AGPRs for the whole loop (no shuttling)
#define MFMA64(AF, BF)                                                       \
  _Pragma("unroll") for (int m_ = 0; m_ < 8; ++m_)                           \
    _Pragma("unroll") for (int n_ = 0; n_ < 8; ++n_)                         \
      asm volatile("v_mfma_f32_16x16x32_bf16 %0, %1, %2, %0"                 \
                   : "+a"(acc[m_][n_]) : "v"(AF[m_]), "v"(BF[n_]));

#define SB  __builtin_amdgcn_sched_barrier(0)
#define BAR __builtin_amdgcn_s_barrier()
#define VM0 asm volatile("s_waitcnt vmcnt(0)" ::: "memory")

  f32x4 acc[8][8];
#pragma unroll
  for (int i = 0; i < 8; ++i)
#pragma unroll
    for (int j = 0; j < 8; ++j) acc[i][j] = (f32x4){0.f, 0.f, 0.f, 0.f};

  const int NT = Kdim >> 6;
  // prologue: stage tile 0 into buf 0; pre-read kk0 frags
  STAGE(1, 0, 0, 0); STAGE(1, 0, 1, 0);
  STAGE(0, 0, 0, 0); STAGE(0, 0, 1, 0);
  VM0; SB; BAR;
  READ_K(0, 0, a0, b0)

  for (int kt = 0; kt < NT; ++kt) {
    const int d = kt & 1;
    const bool more = (kt + 1) < NT;
    // ---- W0: stage t+1; read kk1; MFMA kk0 (frags from previous window) ----
    if (more) {
      STAGE(1, d ^ 1, 0, kt + 1); STAGE(1, d ^ 1, 1, kt + 1);
      STAGE(0, d ^ 1, 0, kt + 1); STAGE(0, d ^ 1, 1, kt + 1);
    }
    READ_K(d, 1, a1, b1)
    SB;
    MFMA64(a0, b0)
    SB; VM0; BAR;            // t+1 staged (issued ~1240cy ago) + visible
    // ---- W1: read next tile's kk0 from other buf; MFMA kk1 ----
    if (more) { READ_K(d ^ 1, 0, a0, b0) }
    SB;
    MFMA64(a1, b1)
    SB; BAR;                 // all reads of buf d consumed; t+2 may overwrite
  }

  // epilogue: D[row=(l>>4)*4+r][col=l&15] per 16x16 frag
#pragma unroll
  for (int m = 0; m < 8; ++m) {
    const int rowb = m0 + wr * 128 + m * 16 + l4 * 4;
#pragma unroll
    for (int n = 0; n < 8; ++n) {
      const int col = n0 + wc * 128 + n * 16 + l15;
      const float bv = bias[col];
      f32x4 v = acc[m][n];
#pragma unroll
      for (int r = 0; r < 4; ++r) {
        float f = v[r] + bv;
        if (RELU) f = fmaxf(f, 0.f);
        Cptr[(size_t)(rowb + r) * Ncols + col] = f2bf(f);
      }
    }
  }
#undef STAGE
#undef READ_K
#undef MFMA64
#undef SB
#undef BAR
#undef VM0
}

// ---------------- combine: out[n] = sum_k gate * y[e_k, p_k] -----------------
__global__ __launch_bounds__(256) void combine_kernel(const ushort* __restrict__ y,
                                                      const int* __restrict__ topi,
                                                      const int* __restrict__ pos,
                                                      const float* __restrict__ gatev,
                                                      float* __restrict__ out) {
  const int lane = threadIdx.x & 63;
  const int n = blockIdx.x * 4 + (threadIdx.x >> 6);
  int i0 = topi[n * 2], i1 = topi[n * 2 + 1];
  int p0 = pos[n * 2], p1 = pos[n * 2 + 1];
  float g0 = (p0 < CAP) ? gatev[n * 2] : 0.f;
  float g1 = (p1 < CAP) ? gatev[n * 2 + 1] : 0.f;
  const ushort* y0 = y + (size_t)(i0 * CAP + (p0 < CAP ? p0 : 0)) * MDIM;
  const ushort* y1 = y + (size_t)(i1 * CAP + (p1 < CAP ? p1 : 0)) * MDIM;
  float* o = out + (size_t)n * MDIM;
#pragma unroll
  for (int c = 0; c < 4; ++c) {
    int idx = c * 256 + lane * 4;
    ushort4 a = *(const ushort4*)(y0 + idx);
    ushort4 b = *(const ushort4*)(y1 + idx);
    float4 ov;
    ov.x = g0 * bf2f(a.x) + g1 * bf2f(b.x);
    ov.y = g0 * bf2f(a.y) + g1 * bf2f(b.y);
    ov.z = g0 * bf2f(a.z) + g1 * bf2f(b.z);
    ov.w = g0 * bf2f(a.w) + g1 * bf2f(b.w);
    *(float4*)(o + idx) = ov;
  }
}

extern "C" void kernel_launch(void* const* d_in, const int* in_sizes, int n_in,
                              void* d_out, int out_size, void* d_ws, size_t ws_size,
                              hipStream_t stream) {
  const float* x  = (const float*)d_in[0];
  const float* wg = (const float*)d_in[1];
  const float* w1 = (const float*)d_in[2];
  const float* b1 = (const float*)d_in[3];
  const float* w2 = (const float*)d_in[4];
  const float* b2 = (const float*)d_in[5];
  float* out = (float*)d_out;
  char* ws = (char*)d_ws;

  // workspace layout (224.3 MB total)
  int*    topi  = (int*)(ws);
  int*    pos   = (int*)(ws + 65536);
  float*  gatev = (float*)(ws + 131072);
  ushort* dispb = (ushort*)(ws + 262144);                          // 32MB, reused as y
  ushort* wT    = (ushort*)(ws + 262144 + 33554432);               // 64MB (w1t then w2t)
  ushort* hbuf  = (ushort*)(ws + 262144 + 33554432 + 67108864);    // 128MB

  gate_kernel<<<NTOK / 4, 256, 0, stream>>>(x, wg, topi, gatev);
  scan_kernel<<<1, 256, 0, stream>>>(topi, pos);
  // no zero_kernel: disp rows p >= count[e] are never read downstream
  scatter_kernel<<<NTOK / 4, 256, 0, stream>>>(x, topi, pos, dispb);

  // FFN layer 1: h = relu(disp @ w1 + b1)   [E,2048,1024]x[E,1024,4096]
  transpose_cvt<<<dim3(HDIM / 64, MDIM / 64, NEXP), 256, 0, stream>>>(w1, wT, MDIM, HDIM);
  gemm4w<true><<<dim3(HDIM / 256, CAP / 256, NEXP), 256, 0, stream>>>(
      dispb, wT, b1, hbuf, CAP, HDIM, MDIM);

  // FFN layer 2: y = h @ w2 + b2            [E,2048,4096]x[E,4096,1024]
  transpose_cvt<<<dim3(MDIM / 64, HDIM / 64, NEXP), 256, 0, stream>>>(w2, wT, HDIM, MDIM);
  ushort* ybuf = dispb;  // dispb is dead after GEMM1
  gemm4w<false><<<dim3(MDIM / 256, CAP / 256, NEXP), 256, 0, stream>>>(
      hbuf, wT, b2, ybuf, CAP, MDIM, HDIM);

  combine_kernel<<<NTOK / 4, 256, 0, stream>>>(ybuf, topi, pos, gatev, out);
}

// Round 12
// 410.317 us; speedup vs baseline: 1.4446x; 1.1814x over previous
//
#include <hip/hip_runtime.h>
#include <hip/hip_bf16.h>
#include <stdint.h>

#define NTOK 8192   // B*S
#define MDIM 1024
#define HDIM 4096
#define NEXP 8
#define CAP  2048   // int(1.0 * 2 * 8192 // 8)

typedef __attribute__((ext_vector_type(8))) short bf16x8;
typedef __attribute__((ext_vector_type(4))) float f32x4;

__device__ __forceinline__ ushort f2bf(float f) {
  uint32_t u = __builtin_bit_cast(uint32_t, f);
  u += 0x7FFFu + ((u >> 16) & 1u);          // round-to-nearest-even
  return (ushort)(u >> 16);
}
__device__ __forceinline__ float bf2f(ushort h) {
  uint32_t u = ((uint32_t)h) << 16;
  return __builtin_bit_cast(float, u);
}

// async global->LDS, 16B per lane; LDS dest = wave-uniform base + lane*16
#define GLOAD_LDS16(g, l)                                                    \
  __builtin_amdgcn_global_load_lds(                                          \
      (const __attribute__((address_space(1))) void*)(g),                    \
      (__attribute__((address_space(3))) void*)(l), 16, 0, 0)

// ---------------- gate: logits = x@wg (f64 accum), softmax-top2, normalize ----
__global__ __launch_bounds__(256) void gate_kernel(const float* __restrict__ x,
                                                   const float* __restrict__ wg,
                                                   int* __restrict__ topi,
                                                   float* __restrict__ gatev) {
  const int lane = threadIdx.x & 63;
  const int n = blockIdx.x * 4 + (threadIdx.x >> 6);   // one wave per token
  const float* xr = x + (size_t)n * MDIM;
  double acc[NEXP];
#pragma unroll
  for (int e = 0; e < NEXP; ++e) acc[e] = 0.0;
#pragma unroll
  for (int c = 0; c < 4; ++c) {
    float4 xv = *(const float4*)(xr + c * 256 + lane * 4);
    float xs[4] = {xv.x, xv.y, xv.z, xv.w};
#pragma unroll
    for (int j = 0; j < 4; ++j) {
      int m = c * 256 + lane * 4 + j;
      float4 w0 = *(const float4*)(wg + m * 8);
      float4 w1 = *(const float4*)(wg + m * 8 + 4);
      double xd = (double)xs[j];
      acc[0] += xd * (double)w0.x; acc[1] += xd * (double)w0.y;
      acc[2] += xd * (double)w0.z; acc[3] += xd * (double)w0.w;
      acc[4] += xd * (double)w1.x; acc[5] += xd * (double)w1.y;
      acc[6] += xd * (double)w1.z; acc[7] += xd * (double)w1.w;
    }
  }
#pragma unroll
  for (int off = 32; off >= 1; off >>= 1) {
#pragma unroll
    for (int e = 0; e < NEXP; ++e) acc[e] += __shfl_xor(acc[e], off, 64);
  }
  if (lane == 0) {
    int i0 = 0;
#pragma unroll
    for (int e = 1; e < NEXP; ++e) if (acc[e] > acc[i0]) i0 = e;
    int i1 = (i0 == 0) ? 1 : 0;
#pragma unroll
    for (int e = 0; e < NEXP; ++e) if (e != i0 && acc[e] > acc[i1]) i1 = e;
    // normalized top-2 of softmax == softmax over the two logits
    double e1 = exp(acc[i1] - acc[i0]);
    double s = 1.0 + e1;
    topi[n * 2 + 0] = i0; topi[n * 2 + 1] = i1;
    gatev[n * 2 + 0] = (float)(1.0 / s);
    gatev[n * 2 + 1] = (float)(e1 / s);
  }
}

// ---------------- slot-major cumulative positions (order: j = k*NTOK + n) ----
__global__ __launch_bounds__(256) void scan_kernel(const int* __restrict__ topi,
                                                   int* __restrict__ pos) {
  __shared__ int cnt[256][NEXP];
  const int t = threadIdx.x;
#pragma unroll
  for (int e = 0; e < NEXP; ++e) cnt[t][e] = 0;
  for (int i = 0; i < 64; ++i) {
    int j = t * 64 + i;
    int e = topi[(j & (NTOK - 1)) * 2 + (j >> 13)];
    cnt[t][e]++;
  }
  __syncthreads();
  if (t < NEXP) {          // exclusive scan over the 256 thread-chunks
    int run = 0;
    for (int i = 0; i < 256; ++i) { int v = cnt[i][t]; cnt[i][t] = run; run += v; }
  }
  __syncthreads();
  for (int i = 0; i < 64; ++i) {
    int j = t * 64 + i;
    int idx = (j & (NTOK - 1)) * 2 + (j >> 13);
    int e = topi[idx];
    pos[idx] = cnt[t][e]++;
  }
}

// ---------------- scatter x rows (bf16) into [E,CAP,M] -----------------------
// No zero-fill of disp needed: rows p >= count[e] are garbage, but the GEMMs
// are row-independent and combine only gathers pos < count[e] <= CAP slots --
// garbage rows are never read by any consumer of the final output.
__global__ __launch_bounds__(256) void scatter_kernel(const float* __restrict__ x,
                                                      const int* __restrict__ topi,
                                                      const int* __restrict__ pos,
                                                      ushort* __restrict__ disp) {
  const int lane = threadIdx.x & 63;
  const int n = blockIdx.x * 4 + (threadIdx.x >> 6);
  const float* src = x + (size_t)n * MDIM;
  ushort b[16];
#pragma unroll
  for (int c = 0; c < 4; ++c) {
    float4 v = *(const float4*)(src + c * 256 + lane * 4);
    b[c * 4 + 0] = f2bf(v.x); b[c * 4 + 1] = f2bf(v.y);
    b[c * 4 + 2] = f2bf(v.z); b[c * 4 + 3] = f2bf(v.w);
  }
#pragma unroll
  for (int k = 0; k < 2; ++k) {
    int p = pos[n * 2 + k];
    if (p < CAP) {
      int e = topi[n * 2 + k];
      ushort* dst = disp + ((size_t)(e * CAP + p)) * MDIM;
#pragma unroll
      for (int c = 0; c < 4; ++c) {
        ushort4 o; o.x = b[c*4+0]; o.y = b[c*4+1]; o.z = b[c*4+2]; o.w = b[c*4+3];
        *(ushort4*)(dst + c * 256 + lane * 4) = o;
      }
    }
  }
}

// ---------------- transpose + f32->bf16: in[R][C] -> out[C][R], per expert ---
__global__ __launch_bounds__(256) void transpose_cvt(const float* __restrict__ in,
                                                     ushort* __restrict__ out,
                                                     int R, int C) {
  __shared__ float tile[64][65];
  const int e = blockIdx.z;
  in  += (size_t)e * R * C;
  out += (size_t)e * R * C;
  const int r0 = blockIdx.y * 64, c0 = blockIdx.x * 64;
  const int t = threadIdx.x;
  const int r = t >> 2, cq = t & 3;
#pragma unroll
  for (int i = 0; i < 4; ++i) {
    float4 v = *(const float4*)(in + (size_t)(r0 + r) * C + c0 + cq * 16 + i * 4);
    tile[r][cq * 16 + i * 4 + 0] = v.x; tile[r][cq * 16 + i * 4 + 1] = v.y;
    tile[r][cq * 16 + i * 4 + 2] = v.z; tile[r][cq * 16 + i * 4 + 3] = v.w;
  }
  __syncthreads();
  const int oc = t >> 2, orr0 = (t & 3) * 16;
  ushort o16[16];
#pragma unroll
  for (int i = 0; i < 16; ++i) o16[i] = f2bf(tile[orr0 + i][oc]);
  ushort* dst = out + (size_t)(c0 + oc) * R + r0 + orr0;
  *(uint4*)dst = *(uint4*)&o16[0];
  *(uint4*)(dst + 8) = *(uint4*)&o16[8];
}

// ============================================================================
// 256x256x64 bf16 GEMM, merged-window schedule (round 12 = round 5 verbatim,
// the best measured GEMM: 137.4us, MfmaUtil 42.6%, 0 bank conflicts).
// Round 9 A/B: setprio = +3% here (keep). Rounds 6-11 explored free-run,
// 32x32 MFMA, cluster-pipeline, 4-wave/AGPR -- all regressed; the 8-wave
// 256^2 structure is balanced at LDS ~2300cy : MFMA ~2480cy per K-tile and
// this schedule is its best realization found.
// Quadrant walk q0=(A0,B0) q1=(A0,B1) q2=(A1,B1) q3=(A1,B0); A-frags held
// across pairs, B0 held q0->q3 (24 ds_read_b128/tile/wave = minimum).
// 2 windows/tile; counted VM4 (VM0 last iter); global_load_lds(16B) with
// pre-swizzled source, linear LDS dest, XOR-swizzled reads.
// ============================================================================
template <bool RELU>
__global__ __launch_bounds__(512, 1) void gemm8p(const ushort* __restrict__ Ag,
                                                 const ushort* __restrict__ Btg,
                                                 const float* __restrict__ biasg,
                                                 ushort* __restrict__ Cout,
                                                 int Mrows, int Ncols, int Kdim) {
  __shared__ ushort sh[65536];   // 128 KiB
  // bijective XCD swizzle (grids are %8==0)
  const int gx = gridDim.x, gy = gridDim.y;
  const int nwg = gx * gy * gridDim.z;
  const int lin = blockIdx.x + gx * (blockIdx.y + gy * blockIdx.z);
  const int cpx = nwg >> 3;
  const int swz = (lin & 7) * cpx + (lin >> 3);
  const int gxy = gx * gy;
  const int ez = swz / gxy;
  const int rem = swz - ez * gxy;
  const int by = rem / gx;
  const int bx = rem - by * gx;

  const ushort* A  = Ag  + (size_t)ez * Mrows * Kdim;
  const ushort* Bt = Btg + (size_t)ez * Ncols * Kdim;
  const float* bias = biasg + (size_t)ez * Ncols;
  ushort* Cptr = Cout + (size_t)ez * Mrows * Ncols;
  const int m0 = by * 256, n0 = bx * 256;
  const int t = threadIdx.x, lane = t & 63, w = t >> 6;
  const int l15 = lane & 15, l4 = lane >> 4;
  const int wr = w >> 2, wc = w & 3;      // 2x4 wave grid over quadrant frags

  // ---- staging addressing ----
  const int srow = lane >> 3;             // 0..7 row within 8-row slab
  const int cs = (lane & 7) ^ srow;       // pre-swizzled source chunk
  const ushort* Abase = A  + (size_t)(m0 + w * 8 + srow) * Kdim + cs * 8;
  const ushort* Bbase = Bt + (size_t)(n0 + w * 8 + srow) * Kdim + cs * 8;
  const int ldsw = w * 512;               // wave-uniform LDS offset (ushorts)

  // stage one half (128 rows x 64 K) of A or B: 2 gloads/thread
#define STAGE8(isA, d, half, ktile)                                          \
  do {                                                                       \
    const ushort* gb = ((isA) ? Abase : Bbase) +                             \
                       (size_t)((half) * 128) * Kdim + (ktile) * 64;         \
    ushort* lb = sh + ((isA) ? 0 : 32768) + ((d) * 2 + (half)) * 8192 + ldsw;\
    GLOAD_LDS16(gb, lb);                                                     \
    GLOAD_LDS16(gb + (size_t)64 * Kdim, lb + 4096);                         \
  } while (0)

  // ---- fragment-read addressing ----
  const int chk0 = ((0 + l4) ^ (l15 & 7)) * 8;   // kk=0 chunk (ushorts)
  const int chk1 = ((4 + l4) ^ (l15 & 7)) * 8;   // kk=1 chunk
  const int aoff = (wr * 64 + l15) * 64;
  const int boff = (wc * 32 + l15) * 64;

  bf16x8 af[8];    // A-frags of current ai: [fr]=kk0, [4+fr]=kk1
  bf16x8 b0[4];    // B0 frags: [fc]=kk0, [2+fc]=kk1 (held q0->q3)
  bf16x8 b1[4];    // B1 frags

#define READ_A(d, ai)                                                        \
  { const ushort* Ar = sh + ((d) * 2 + (ai)) * 8192 + aoff;                  \
    _Pragma("unroll") for (int fr = 0; fr < 4; ++fr) {                       \
      af[fr]     = *(const bf16x8*)(Ar + fr * 1024 + chk0);                  \
      af[4 + fr] = *(const bf16x8*)(Ar + fr * 1024 + chk1);                  \
    } }

#define READ_B(d, bj, dst)                                                   \
  { const ushort* Br = sh + 32768 + ((d) * 2 + (bj)) * 8192 + boff;          \
    _Pragma("unroll") for (int fc = 0; fc < 2; ++fc) {                       \
      dst[fc]     = *(const bf16x8*)(Br + fc * 1024 + chk0);                 \
      dst[2 + fc] = *(const bf16x8*)(Br + fc * 1024 + chk1);                 \
    } }

#define MFMA_Q(ai, bj, BR)                                                   \
  __builtin_amdgcn_s_setprio(1);                                             \
  _Pragma("unroll") for (int fr = 0; fr < 4; ++fr)                           \
    _Pragma("unroll") for (int fc = 0; fc < 2; ++fc) {                       \
      acc[(ai) * 4 + fr][(bj) * 2 + fc] =                                    \
          __builtin_amdgcn_mfma_f32_16x16x32_bf16(                           \
              af[fr], BR[fc], acc[(ai) * 4 + fr][(bj) * 2 + fc], 0, 0, 0);   \
      acc[(ai) * 4 + fr][(bj) * 2 + fc] =                                    \
          __builtin_amdgcn_mfma_f32_16x16x32_bf16(                           \
              af[4 + fr], BR[2 + fc], acc[(ai) * 4 + fr][(bj) * 2 + fc],     \
              0, 0, 0);                                                      \
    }                                                                        \
  __builtin_amdgcn_s_setprio(0);

#define SB  __builtin_amdgcn_sched_barrier(0)
#define BAR __builtin_amdgcn_s_barrier()
#define VM4 asm volatile("s_waitcnt vmcnt(4)" ::: "memory")
#define VM0 asm volatile("s_waitcnt vmcnt(0)" ::: "memory")

  f32x4 acc[8][4];
#pragma unroll
  for (int i = 0; i < 8; ++i)
#pragma unroll
    for (int j = 0; j < 4; ++j) acc[i][j] = (f32x4){0.f, 0.f, 0.f, 0.f};

  const int NT = Kdim >> 6;
  const int NI = NT >> 1;
  // prologue: tile0 all 4 halves + tile1 A0,B1 (steady-state invariant)
  STAGE8(1, 0, 0, 0);
  STAGE8(0, 0, 1, 0);
  STAGE8(1, 0, 1, 0);
  STAGE8(0, 0, 0, 0);
  STAGE8(1, 1, 0, 1);
  STAGE8(0, 1, 1, 1);
  VM4;           // 12 outstanding -> drains tile0's 8; tile1 A0,B1 in flight
  SB; BAR;

  for (int t2 = 0; t2 < NI; ++t2) {
    const int tb = 2 * t2;
    const bool g2 = (t2 + 1) < NI;     // tiles tb+2, tb+3 exist
    const bool last = (t2 == NI - 1);
    // ---- W0: tile tb (buf0), q0+q1 ----
    READ_A(0, 0) READ_B(0, 0, b0)
    STAGE8(1, 1, 1, tb + 1);           // A1 of t+1 -> d1
    STAGE8(0, 1, 0, tb + 1);           // B0 of t+1 -> d1
    READ_B(0, 1, b1)
    MFMA_Q(0, 0, b0)
    MFMA_Q(0, 1, b1)
    SB; BAR;
    // ---- W1: tile tb, q2+q3 ----
    READ_A(0, 1)
    if (g2) { STAGE8(1, 0, 0, tb + 2); STAGE8(0, 0, 1, tb + 2); } // A0,B1 t+2 -> d0
    MFMA_Q(1, 1, b1)
    MFMA_Q(1, 0, b0)
    SB;
    if (last) { VM0; } else { VM4; }   // t+1 (d1) fully staged after this
    BAR;
    // ---- W2: tile tb+1 (buf1), q0+q1 ----
    READ_A(1, 0) READ_B(1, 0, b0)
    if (g2) { STAGE8(1, 0, 1, tb + 2); STAGE8(0, 0, 0, tb + 2); } // A1,B0 t+2 -> d0
    READ_B(1, 1, b1)
    MFMA_Q(0, 0, b0)
    MFMA_Q(0, 1, b1)
    SB; BAR;
    // ---- W3: tile tb+1, q2+q3 ----
    READ_A(1, 1)
    if (g2) { STAGE8(1, 1, 0, tb + 3); STAGE8(0, 1, 1, tb + 3); } // A0,B1 t+3 -> d1
    MFMA_Q(1, 1, b1)
    MFMA_Q(1, 0, b0)
    SB; VM4; BAR;                      // t+2 (d0) fully staged after this
  }

  // epilogue: D[row=(l>>4)*4+r][col=l&15] per 16x16 frag
#pragma unroll
  for (int ai = 0; ai < 2; ++ai)
#pragma unroll
    for (int fr = 0; fr < 4; ++fr) {
      const int rowb = m0 + ai * 128 + wr * 64 + fr * 16 + l4 * 4;
#pragma unroll
      for (int bj = 0; bj < 2; ++bj)
#pragma unroll
        for (int fc = 0; fc < 2; ++fc) {
          const int col = n0 + bj * 128 + wc * 32 + fc * 16 + l15;
          const float bv = bias[col];
          f32x4 v = acc[ai * 4 + fr][bj * 2 + fc];
#pragma unroll
          for (int r = 0; r < 4; ++r) {
            float f = v[r] + bv;
            if (RELU) f = fmaxf(f, 0.f);
            Cptr[(size_t)(rowb + r) * Ncols + col] = f2bf(f);
          }
        }
    }
#undef STAGE8
#undef READ_A
#undef READ_B
#undef MFMA_Q
#undef SB
#undef BAR
#undef VM4
#undef VM0
}

// ---------------- combine: out[n] = sum_k gate * y[e_k, p_k] -----------------
__global__ __launch_bounds__(256) void combine_kernel(const ushort* __restrict__ y,
                                                      const int* __restrict__ topi,
                                                      const int* __restrict__ pos,
                                                      const float* __restrict__ gatev,
                                                      float* __restrict__ out) {
  const int lane = threadIdx.x & 63;
  const int n = blockIdx.x * 4 + (threadIdx.x >> 6);
  int i0 = topi[n * 2], i1 = topi[n * 2 + 1];
  int p0 = pos[n * 2], p1 = pos[n * 2 + 1];
  float g0 = (p0 < CAP) ? gatev[n * 2] : 0.f;
  float g1 = (p1 < CAP) ? gatev[n * 2 + 1] : 0.f;
  const ushort* y0 = y + (size_t)(i0 * CAP + (p0 < CAP ? p0 : 0)) * MDIM;
  const ushort* y1 = y + (size_t)(i1 * CAP + (p1 < CAP ? p1 : 0)) * MDIM;
  float* o = out + (size_t)n * MDIM;
#pragma unroll
  for (int c = 0; c < 4; ++c) {
    int idx = c * 256 + lane * 4;
    ushort4 a = *(const ushort4*)(y0 + idx);
    ushort4 b = *(const ushort4*)(y1 + idx);
    float4 ov;
    ov.x = g0 * bf2f(a.x) + g1 * bf2f(b.x);
    ov.y = g0 * bf2f(a.y) + g1 * bf2f(b.y);
    ov.z = g0 * bf2f(a.z) + g1 * bf2f(b.z);
    ov.w = g0 * bf2f(a.w) + g1 * bf2f(b.w);
    *(float4*)(o + idx) = ov;
  }
}

extern "C" void kernel_launch(void* const* d_in, const int* in_sizes, int n_in,
                              void* d_out, int out_size, void* d_ws, size_t ws_size,
                              hipStream_t stream) {
  const float* x  = (const float*)d_in[0];
  const float* wg = (const float*)d_in[1];
  const float* w1 = (const float*)d_in[2];
  const float* b1 = (const float*)d_in[3];
  const float* w2 = (const float*)d_in[4];
  const float* b2 = (const float*)d_in[5];
  float* out = (float*)d_out;
  char* ws = (char*)d_ws;

  // workspace layout (224.3 MB total)
  int*    topi  = (int*)(ws);
  int*    pos   = (int*)(ws + 65536);
  float*  gatev = (float*)(ws + 131072);
  ushort* dispb = (ushort*)(ws + 262144);                          // 32MB, reused as y
  ushort* wT    = (ushort*)(ws + 262144 + 33554432);               // 64MB (w1t then w2t)
  ushort* hbuf  = (ushort*)(ws + 262144 + 33554432 + 67108864);    // 128MB

  gate_kernel<<<NTOK / 4, 256, 0, stream>>>(x, wg, topi, gatev);
  scan_kernel<<<1, 256, 0, stream>>>(topi, pos);
  // no zero_kernel: disp rows p >= count[e] are never read downstream
  scatter_kernel<<<NTOK / 4, 256, 0, stream>>>(x, topi, pos, dispb);

  // FFN layer 1: h = relu(disp @ w1 + b1)   [E,2048,1024]x[E,1024,4096]
  transpose_cvt<<<dim3(HDIM / 64, MDIM / 64, NEXP), 256, 0, stream>>>(w1, wT, MDIM, HDIM);
  gemm8p<true><<<dim3(HDIM / 256, CAP / 256, NEXP), 512, 0, stream>>>(
      dispb, wT, b1, hbuf, CAP, HDIM, MDIM);

  // FFN layer 2: y = h @ w2 + b2            [E,2048,4096]x[E,4096,1024]
  transpose_cvt<<<dim3(MDIM / 64, HDIM / 64, NEXP), 256, 0, stream>>>(w2, wT, HDIM, MDIM);
  ushort* ybuf = dispb;  // dispb is dead after GEMM1
  gemm8p<false><<<dim3(MDIM / 256, CAP / 256, NEXP), 512, 0, stream>>>(
      hbuf, wT, b2, ybuf, CAP, MDIM, HDIM);

  combine_kernel<<<NTOK / 4, 256, 0, stream>>>(ybuf, topi, pos, gatev, out);
}